// Round 10
// baseline (480.203 us; speedup 1.0000x reference)
//
#include <hip/hip_runtime.h>

// GCN 2-layer via CSR gather. R10: binned two-phase CSR placement — k_place's
// 53us was random-scatter-line write traffic (54MB for 3.2MB payload);
// bin-append (lines filled 8/8) + L2-local placement (bin window ~32KB) fixes it.
// GEMM k-loops kept ROLLED (#pragma unroll 1): full unroll -> 512 VGPR spill storm.
constexpr int N  = 100000;
constexpr int E  = 800000;
constexpr int CHUNK = 1024;
constexpr int NB = (N + CHUNK - 1) / CHUNK;   // 98 scan blocks
constexpr int NBINS = 98;                     // bin = dst >> 10
constexpr int NSUB  = 4;                      // sub-buffers per bin (contention spread)
constexpr int BCAP  = 3072;                   // per (bin,sub) capacity; mean 2048, ~22 sigma

// ---------------- bin pass (fused degree): 4 edges/thread ----------------
__global__ void k_bin(const int* __restrict__ src, const int* __restrict__ dst,
                      int* __restrict__ deg, int* __restrict__ bincnt,
                      unsigned long long* __restrict__ binbuf) {
    int t = blockIdx.x * blockDim.x + threadIdx.x;
    int e = t * 4;
    int s = threadIdx.x & (NSUB - 1);
    if (e + 3 < E) {
        int4 s4 = *(const int4*)(src + e);
        int4 d4 = *(const int4*)(dst + e);
        atomicAdd(&deg[d4.x], 1);
        atomicAdd(&deg[d4.y], 1);
        atomicAdd(&deg[d4.z], 1);
        atomicAdd(&deg[d4.w], 1);
        int b0 = (d4.x >> 10) * NSUB + s;
        int b1 = (d4.y >> 10) * NSUB + s;
        int b2 = (d4.z >> 10) * NSUB + s;
        int b3 = (d4.w >> 10) * NSUB + s;
        int p0 = atomicAdd(&bincnt[b0], 1);
        int p1 = atomicAdd(&bincnt[b1], 1);
        int p2 = atomicAdd(&bincnt[b2], 1);
        int p3 = atomicAdd(&bincnt[b3], 1);
        if (p0 < BCAP) binbuf[(long)b0 * BCAP + p0] =
            ((unsigned long long)(unsigned)d4.x << 32) | (unsigned)s4.x;
        if (p1 < BCAP) binbuf[(long)b1 * BCAP + p1] =
            ((unsigned long long)(unsigned)d4.y << 32) | (unsigned)s4.y;
        if (p2 < BCAP) binbuf[(long)b2 * BCAP + p2] =
            ((unsigned long long)(unsigned)d4.z << 32) | (unsigned)s4.z;
        if (p3 < BCAP) binbuf[(long)b3 * BCAP + p3] =
            ((unsigned long long)(unsigned)d4.w << 32) | (unsigned)s4.w;
    } else {
        for (int k = e; k < E; ++k) {
            int d = dst[k], sc = src[k];
            atomicAdd(&deg[d], 1);
            int b = (d >> 10) * NSUB + s;
            int p = atomicAdd(&bincnt[b], 1);
            if (p < BCAP) binbuf[(long)b * BCAP + p] =
                ((unsigned long long)(unsigned)d << 32) | (unsigned)sc;
        }
    }
}

// ---------------- exclusive scan of deg -> rowptr ----------------
__global__ void k_scanA(const int* __restrict__ deg, int* __restrict__ rowptr,
                        int* __restrict__ bsum) {
    __shared__ int a[2][256];
    int b = blockIdx.x, t = threadIdx.x;
    int base = b * CHUNK + t * 4;
    int v[4];
#pragma unroll
    for (int k = 0; k < 4; ++k) v[k] = (base + k < N) ? deg[base + k] : 0;
    int mysum = v[0] + v[1] + v[2] + v[3];
    a[0][t] = mysum;
    __syncthreads();
    int pin = 0;
    for (int off = 1; off < 256; off <<= 1) {
        int x = a[pin][t];
        if (t >= off) x += a[pin][t - off];
        a[pin ^ 1][t] = x;
        __syncthreads();
        pin ^= 1;
    }
    int incl = a[pin][t];
    int run = incl - mysum;
#pragma unroll
    for (int k = 0; k < 4; ++k) {
        if (base + k < N) rowptr[base + k] = run;
        run += v[k];
    }
    if (t == 255) bsum[b] = incl;
}

// scanC: adds global chunk offset (computed in-block from bsum), writes cursor + dis
__global__ void k_scanC(int* __restrict__ rowptr, const int* __restrict__ bsum,
                        int* __restrict__ cursor, const int* __restrict__ deg,
                        float* __restrict__ dis) {
    __shared__ int s_off;
    int cid = blockIdx.x >> 2;            // 256-node block -> 1024-node chunk
    if (threadIdx.x == 0) {
        int run = 0;
        for (int i = 0; i < cid; ++i) run += bsum[i];
        s_off = run;
    }
    __syncthreads();
    int i = blockIdx.x * blockDim.x + threadIdx.x;
    if (i < N) {
        int r = rowptr[i] + s_off;
        rowptr[i] = r;
        cursor[i] = r;
        dis[i] = rsqrtf((float)(deg[i] + 1));   // +1 self-loop
    }
}

// ---------------- place2: one block per (bin,sub); ecol window L2-local ------
__global__ void k_place2(const unsigned long long* __restrict__ binbuf,
                         const int* __restrict__ bincnt,
                         int* __restrict__ cursor, int* __restrict__ ecol) {
    int bs = blockIdx.x;                  // 0 .. NBINS*NSUB-1
    int cnt = bincnt[bs];
    if (cnt > BCAP) cnt = BCAP;
    const unsigned long long* buf = binbuf + (long)bs * BCAP;
    for (int i = threadIdx.x; i < cnt; i += 512) {
        unsigned long long p = buf[i];
        int sc = (int)(unsigned)p;
        int d  = (int)(p >> 32);
        int pos = atomicAdd(&cursor[d], 1);
        ecol[pos] = sc;
    }
}

// ---------------- GEMM 64->64: H[N,64] = X[N,64] @ W[64,64] ----------------
__global__ __launch_bounds__(256, 2)
void k_gemm64(const float* __restrict__ X, const float* __restrict__ W,
              float* __restrict__ H) {
    __shared__ float sX[64][68];    // 272B rows: float4-aligned, 2-way banks (free)
    __shared__ float sW[64 * 64];
    int row0 = blockIdx.x * 64;
    for (int i = threadIdx.x; i < 64 * 64; i += 256) sW[i] = W[i];
    for (int i4 = threadIdx.x; i4 < 64 * 16; i4 += 256) {
        int r = i4 >> 4, c4 = i4 & 15;
        int gr = row0 + r;
        float4 v = make_float4(0.f, 0.f, 0.f, 0.f);
        if (gr < N) v = *(const float4*)(X + (long)gr * 64 + c4 * 4);
        *(float4*)&sX[r][c4 * 4] = v;
    }
    __syncthreads();

    int ty = threadIdx.x >> 4, tx = threadIdx.x & 15;
    int r0 = ty * 4, c0 = tx * 4;
    float4 acc0 = make_float4(0.f, 0.f, 0.f, 0.f);
    float4 acc1 = acc0, acc2 = acc0, acc3 = acc0;

#pragma unroll 1
    for (int k = 0; k < 64; k += 4) {
        float4 a0 = *(const float4*)&sX[r0 + 0][k];
        float4 a1 = *(const float4*)&sX[r0 + 1][k];
        float4 a2 = *(const float4*)&sX[r0 + 2][k];
        float4 a3 = *(const float4*)&sX[r0 + 3][k];
        float4 b0 = *(const float4*)&sW[(k + 0) * 64 + c0];
        float4 b1 = *(const float4*)&sW[(k + 1) * 64 + c0];
        float4 b2 = *(const float4*)&sW[(k + 2) * 64 + c0];
        float4 b3 = *(const float4*)&sW[(k + 3) * 64 + c0];
        acc0.x += a0.x*b0.x + a0.y*b1.x + a0.z*b2.x + a0.w*b3.x;
        acc0.y += a0.x*b0.y + a0.y*b1.y + a0.z*b2.y + a0.w*b3.y;
        acc0.z += a0.x*b0.z + a0.y*b1.z + a0.z*b2.z + a0.w*b3.z;
        acc0.w += a0.x*b0.w + a0.y*b1.w + a0.z*b2.w + a0.w*b3.w;
        acc1.x += a1.x*b0.x + a1.y*b1.x + a1.z*b2.x + a1.w*b3.x;
        acc1.y += a1.x*b0.y + a1.y*b1.y + a1.z*b2.y + a1.w*b3.y;
        acc1.z += a1.x*b0.z + a1.y*b1.z + a1.z*b2.z + a1.w*b3.z;
        acc1.w += a1.x*b0.w + a1.y*b1.w + a1.z*b2.w + a1.w*b3.w;
        acc2.x += a2.x*b0.x + a2.y*b1.x + a2.z*b2.x + a2.w*b3.x;
        acc2.y += a2.x*b0.y + a2.y*b1.y + a2.z*b2.y + a2.w*b3.y;
        acc2.z += a2.x*b0.z + a2.y*b1.z + a2.z*b2.z + a2.w*b3.z;
        acc2.w += a2.x*b0.w + a2.y*b1.w + a2.z*b2.w + a2.w*b3.w;
        acc3.x += a3.x*b0.x + a3.y*b1.x + a3.z*b2.x + a3.w*b3.x;
        acc3.y += a3.x*b0.y + a3.y*b1.y + a3.z*b2.y + a3.w*b3.y;
        acc3.z += a3.x*b0.z + a3.y*b1.z + a3.z*b2.z + a3.w*b3.z;
        acc3.w += a3.x*b0.w + a3.y*b1.w + a3.z*b2.w + a3.w*b3.w;
    }
    int gr = row0 + r0;
    if (gr + 0 < N) *(float4*)(H + (long)(gr + 0) * 64 + c0) = acc0;
    if (gr + 1 < N) *(float4*)(H + (long)(gr + 1) * 64 + c0) = acc1;
    if (gr + 2 < N) *(float4*)(H + (long)(gr + 2) * 64 + c0) = acc2;
    if (gr + 3 < N) *(float4*)(H + (long)(gr + 3) * 64 + c0) = acc3;
}

// ---------------- GEMM 64->32: H[N,32] = X[N,64] @ W[64,32] ----------------
__global__ __launch_bounds__(256, 2)
void k_gemm32(const float* __restrict__ X, const float* __restrict__ W,
              float* __restrict__ H) {
    __shared__ float sX[64][68];
    __shared__ float sW[64 * 32];
    int row0 = blockIdx.x * 64;
    for (int i = threadIdx.x; i < 64 * 32; i += 256) sW[i] = W[i];
    for (int i4 = threadIdx.x; i4 < 64 * 16; i4 += 256) {
        int r = i4 >> 4, c4 = i4 & 15;
        int gr = row0 + r;
        float4 v = make_float4(0.f, 0.f, 0.f, 0.f);
        if (gr < N) v = *(const float4*)(X + (long)gr * 64 + c4 * 4);
        *(float4*)&sX[r][c4 * 4] = v;
    }
    __syncthreads();

    int ty = threadIdx.x >> 4, tx = threadIdx.x & 15;
    int r0 = ty * 4, c0 = tx * 2;
    float2 acc0 = make_float2(0.f, 0.f);
    float2 acc1 = acc0, acc2 = acc0, acc3 = acc0;

#pragma unroll 1
    for (int k = 0; k < 64; k += 4) {
        float4 a0 = *(const float4*)&sX[r0 + 0][k];
        float4 a1 = *(const float4*)&sX[r0 + 1][k];
        float4 a2 = *(const float4*)&sX[r0 + 2][k];
        float4 a3 = *(const float4*)&sX[r0 + 3][k];
        float2 b0 = *(const float2*)&sW[(k + 0) * 32 + c0];
        float2 b1 = *(const float2*)&sW[(k + 1) * 32 + c0];
        float2 b2 = *(const float2*)&sW[(k + 2) * 32 + c0];
        float2 b3 = *(const float2*)&sW[(k + 3) * 32 + c0];
        acc0.x += a0.x*b0.x + a0.y*b1.x + a0.z*b2.x + a0.w*b3.x;
        acc0.y += a0.x*b0.y + a0.y*b1.y + a0.z*b2.y + a0.w*b3.y;
        acc1.x += a1.x*b0.x + a1.y*b1.x + a1.z*b2.x + a1.w*b3.x;
        acc1.y += a1.x*b0.y + a1.y*b1.y + a1.z*b2.y + a1.w*b3.y;
        acc2.x += a2.x*b0.x + a2.y*b1.x + a2.z*b2.x + a2.w*b3.x;
        acc2.y += a2.x*b0.y + a2.y*b1.y + a2.z*b2.y + a2.w*b3.y;
        acc3.x += a3.x*b0.x + a3.y*b1.x + a3.z*b2.x + a3.w*b3.x;
        acc3.y += a3.x*b0.y + a3.y*b1.y + a3.z*b2.y + a3.w*b3.y;
    }
    int gr = row0 + r0;
    if (gr + 0 < N) *(float2*)(H + (long)(gr + 0) * 32 + c0) = acc0;
    if (gr + 1 < N) *(float2*)(H + (long)(gr + 1) * 32 + c0) = acc1;
    if (gr + 2 < N) *(float2*)(H + (long)(gr + 2) * 32 + c0) = acc2;
    if (gr + 3 < N) *(float2*)(H + (long)(gr + 3) * 32 + c0) = acc3;
}

// ---------------- gather layer 1 (C=64): one wave per node ----------------
// lane = g*16 + q : g = edge slot group (0..3), q = channel quarter (float4)
// All __shfl ops execute with FULL exec mask; lanes >= cnt hold se=0,we=0.
__global__ void k_gather1(const float* __restrict__ h1, const float* __restrict__ dis,
                          const int* __restrict__ rowptr, const int* __restrict__ deg,
                          const int* __restrict__ ecol,
                          const float* __restrict__ b1, float* __restrict__ agg1) {
    int node = (blockIdx.x << 2) + (threadIdx.x >> 6);
    int lane = threadIdx.x & 63;
    if (node >= N) return;                 // wave-uniform (N % 4 == 0)
    int q = lane & 15;
    int g = lane >> 4;
    int start = rowptr[node];
    int dgr = deg[node];
    float di = dis[node];
    float4 acc = make_float4(0.f, 0.f, 0.f, 0.f);

    for (int base = 0; base < dgr; base += 64) {
        int cnt = min(dgr - base, 64);
        int se = 0; float we = 0.f;
        if (lane < cnt) { se = ecol[start + base + lane]; we = dis[se]; }
        for (int j = 0; j < cnt; j += 8) {
            int s0 = __shfl(se, j + g);       float w0 = __shfl(we, j + g);
            int s1 = __shfl(se, j + 4 + g);   float w1 = __shfl(we, j + 4 + g);
            float4 v0 = *(const float4*)(h1 + ((long)s0 << 6) + q * 4);
            float4 v1 = *(const float4*)(h1 + ((long)s1 << 6) + q * 4);
            acc.x += w0 * v0.x + w1 * v1.x;
            acc.y += w0 * v0.y + w1 * v1.y;
            acc.z += w0 * v0.z + w1 * v1.z;
            acc.w += w0 * v0.w + w1 * v1.w;
        }
    }
#pragma unroll
    for (int off = 16; off <= 32; off <<= 1) {
        acc.x += __shfl_xor(acc.x, off);
        acc.y += __shfl_xor(acc.y, off);
        acc.z += __shfl_xor(acc.z, off);
        acc.w += __shfl_xor(acc.w, off);
    }
    if (g == 0) {
        float4 hv = *(const float4*)(h1 + ((long)node << 6) + q * 4);
        float4 bb = *(const float4*)(b1 + q * 4);
        float4 r;
        r.x = fmaxf(di * (acc.x + di * hv.x) + bb.x, 0.f);
        r.y = fmaxf(di * (acc.y + di * hv.y) + bb.y, 0.f);
        r.z = fmaxf(di * (acc.z + di * hv.z) + bb.z, 0.f);
        r.w = fmaxf(di * (acc.w + di * hv.w) + bb.w, 0.f);
        *(float4*)(agg1 + ((long)node << 6) + q * 4) = r;
    }
}

// ---------------- gather layer 2 (C=32) + log_softmax: one wave per node ------
__global__ void k_gather2(const float* __restrict__ h2, const float* __restrict__ dis,
                          const int* __restrict__ rowptr, const int* __restrict__ deg,
                          const int* __restrict__ ecol,
                          const float* __restrict__ b2, float* __restrict__ out) {
    int node = (blockIdx.x << 2) + (threadIdx.x >> 6);
    int lane = threadIdx.x & 63;
    if (node >= N) return;
    int q = lane & 7;
    int g = lane >> 3;
    int start = rowptr[node];
    int dgr = deg[node];
    float di = dis[node];
    float4 acc = make_float4(0.f, 0.f, 0.f, 0.f);

    for (int base = 0; base < dgr; base += 64) {
        int cnt = min(dgr - base, 64);
        int se = 0; float we = 0.f;
        if (lane < cnt) { se = ecol[start + base + lane]; we = dis[se]; }
        for (int j = 0; j < cnt; j += 16) {
            int s0 = __shfl(se, j + g);       float w0 = __shfl(we, j + g);
            int s1 = __shfl(se, j + 8 + g);   float w1 = __shfl(we, j + 8 + g);
            float4 v0 = *(const float4*)(h2 + ((long)s0 << 5) + q * 4);
            float4 v1 = *(const float4*)(h2 + ((long)s1 << 5) + q * 4);
            acc.x += w0 * v0.x + w1 * v1.x;
            acc.y += w0 * v0.y + w1 * v1.y;
            acc.z += w0 * v0.z + w1 * v1.z;
            acc.w += w0 * v0.w + w1 * v1.w;
        }
    }
#pragma unroll
    for (int off = 8; off <= 32; off <<= 1) {
        acc.x += __shfl_xor(acc.x, off);
        acc.y += __shfl_xor(acc.y, off);
        acc.z += __shfl_xor(acc.z, off);
        acc.w += __shfl_xor(acc.w, off);
    }
    float4 hv = *(const float4*)(h2 + ((long)node << 5) + q * 4);
    float4 bb = *(const float4*)(b2 + q * 4);
    float4 v;
    v.x = di * (acc.x + di * hv.x) + bb.x;
    v.y = di * (acc.y + di * hv.y) + bb.y;
    v.z = di * (acc.z + di * hv.z) + bb.z;
    v.w = di * (acc.w + di * hv.w) + bb.w;
    float m = fmaxf(fmaxf(v.x, v.y), fmaxf(v.z, v.w));
#pragma unroll
    for (int off = 1; off <= 4; off <<= 1) m = fmaxf(m, __shfl_xor(m, off));
    float s = expf(v.x - m) + expf(v.y - m) + expf(v.z - m) + expf(v.w - m);
#pragma unroll
    for (int off = 1; off <= 4; off <<= 1) s += __shfl_xor(s, off);
    float lg = m + logf(s);
    if (g == 0) {
        float4 r;
        r.x = v.x - lg; r.y = v.y - lg; r.z = v.z - lg; r.w = v.w - lg;
        *(float4*)(out + ((long)node << 5) + q * 4) = r;
    }
}

extern "C" void kernel_launch(void* const* d_in, const int* in_sizes, int n_in,
                              void* d_out, int out_size, void* d_ws, size_t ws_size,
                              hipStream_t stream) {
    const float* x  = (const float*)d_in[0];
    const int*   ei = (const int*)d_in[1];
    const float* W1 = (const float*)d_in[2];
    const float* b1 = (const float*)d_in[3];
    const float* W2 = (const float*)d_in[4];
    const float* b2 = (const float*)d_in[5];
    float* out = (float*)d_out;

    const int* src = ei;
    const int* dst = ei + E;

    char* w = (char*)d_ws;
    int*   deg    = (int*)(w + 0);
    float* dis    = (float*)(w + (512u << 10));
    int*   rowptr = (int*)(w + (1024u << 10));
    int*   cursor = (int*)(w + (1536u << 10));
    int*   bsum   = (int*)(w + (2048u << 10));
    int*   bincnt = (int*)(w + (2048u << 10) + 4096);          // 392 ints
    int*   ecol   = (int*)(w + (2560u << 10));                 // 3.2 MB
    float* h1     = (float*)(w + (10240u << 10));              // 25.6 MB (reused as h2)
    unsigned long long* binbuf = (unsigned long long*)h1;      // 9.2 MB, dead before gemm64
    float* agg1   = (float*)(w + (36864u << 10));              // 25.6 MB
    float* h2     = h1;                                        // h1 dead after gather1

    hipMemsetAsync(deg, 0, (size_t)N * 4, stream);
    hipMemsetAsync(bincnt, 0, (size_t)NBINS * NSUB * 4, stream);

    k_bin<<<(E / 4 + 255) / 256, 256, 0, stream>>>(src, dst, deg, bincnt, binbuf);
    k_scanA<<<NB, 256, 0, stream>>>(deg, rowptr, bsum);
    k_scanC<<<(N + 255) / 256, 256, 0, stream>>>(rowptr, bsum, cursor, deg, dis);
    k_place2<<<NBINS * NSUB, 512, 0, stream>>>(binbuf, bincnt, cursor, ecol);

    k_gemm64<<<(N + 63) / 64, 256, 0, stream>>>(x, W1, h1);
    k_gather1<<<(N + 3) / 4, 256, 0, stream>>>(h1, dis, rowptr, deg, ecol, b1, agg1);

    k_gemm32<<<(N + 63) / 64, 256, 0, stream>>>(agg1, W2, h2);
    k_gather2<<<(N + 3) / 4, 256, 0, stream>>>(h2, dis, rowptr, deg, ecol, b2, out);
}

// Round 11
// 212.576 us; speedup vs baseline: 2.2590x; 2.2590x over previous
//
#include <hip/hip_runtime.h>

// GCN 2-layer via CSR gather. R11 = R9 (best, 213us) + heterogeneous fusion:
// k_place (TCC-scatter-bound, 53us, resists ILP/binning) overlapped with
// k_gemm64 (VALU/LDS-bound, ~15us) in one grid — place blocks first.
// GEMM k-loops kept ROLLED (#pragma unroll 1): full unroll -> 512 VGPR spill storm.
constexpr int N  = 100000;
constexpr int E  = 800000;
constexpr int CHUNK = 1024;
constexpr int NB = (N + CHUNK - 1) / CHUNK;     // 98 scan blocks
constexpr int PLACE_BLOCKS = (E / 4 + 255) / 256;   // 782
constexpr int GEMM_BLOCKS  = (N + 63) / 64;         // 1563

// ---------------- degree (4 edges/thread) ----------------
__global__ void k_degree(const int* __restrict__ dst, int* __restrict__ deg) {
    int t = blockIdx.x * blockDim.x + threadIdx.x;
    int e = t * 4;
    if (e + 3 < E) {
        int4 d4 = *(const int4*)(dst + e);
        atomicAdd(&deg[d4.x], 1);
        atomicAdd(&deg[d4.y], 1);
        atomicAdd(&deg[d4.z], 1);
        atomicAdd(&deg[d4.w], 1);
    } else {
        for (int k = e; k < E; ++k) atomicAdd(&deg[dst[k]], 1);
    }
}

// ---------------- exclusive scan of deg -> rowptr ----------------
__global__ void k_scanA(const int* __restrict__ deg, int* __restrict__ rowptr,
                        int* __restrict__ bsum) {
    __shared__ int a[2][256];
    int b = blockIdx.x, t = threadIdx.x;
    int base = b * CHUNK + t * 4;
    int v[4];
#pragma unroll
    for (int k = 0; k < 4; ++k) v[k] = (base + k < N) ? deg[base + k] : 0;
    int mysum = v[0] + v[1] + v[2] + v[3];
    a[0][t] = mysum;
    __syncthreads();
    int pin = 0;
    for (int off = 1; off < 256; off <<= 1) {
        int x = a[pin][t];
        if (t >= off) x += a[pin][t - off];
        a[pin ^ 1][t] = x;
        __syncthreads();
        pin ^= 1;
    }
    int incl = a[pin][t];
    int run = incl - mysum;
#pragma unroll
    for (int k = 0; k < 4; ++k) {
        if (base + k < N) rowptr[base + k] = run;
        run += v[k];
    }
    if (t == 255) bsum[b] = incl;
}

// scanC: adds global chunk offset (computed in-block from bsum), writes cursor + dis
__global__ void k_scanC(int* __restrict__ rowptr, const int* __restrict__ bsum,
                        int* __restrict__ cursor, const int* __restrict__ deg,
                        float* __restrict__ dis) {
    __shared__ int s_off;
    int cid = blockIdx.x >> 2;            // 256-node block -> 1024-node chunk
    if (threadIdx.x == 0) {
        int run = 0;
        for (int i = 0; i < cid; ++i) run += bsum[i];
        s_off = run;
    }
    __syncthreads();
    int i = blockIdx.x * blockDim.x + threadIdx.x;
    if (i < N) {
        int r = rowptr[i] + s_off;
        rowptr[i] = r;
        cursor[i] = r;
        dis[i] = rsqrtf((float)(deg[i] + 1));   // +1 self-loop
    }
}

// -------- FUSED: blocks [0,PLACE_BLOCKS) = CSR place; rest = GEMM 64->64 --------
__global__ __launch_bounds__(256, 2)
void k_place_gemm64(const int* __restrict__ src, const int* __restrict__ dst,
                    int* __restrict__ cursor, int* __restrict__ ecol,
                    const float* __restrict__ X, const float* __restrict__ W,
                    float* __restrict__ H) {
    __shared__ float sX[64][68];
    __shared__ float sW[64 * 64];
    if (blockIdx.x < PLACE_BLOCKS) {
        // ---- CSR placement: 4 edges/thread, 4 independent atomic chains ----
        int t = blockIdx.x * 256 + threadIdx.x;
        int e = t * 4;
        if (e + 3 < E) {
            int4 s4 = *(const int4*)(src + e);
            int4 d4 = *(const int4*)(dst + e);
            int p0 = atomicAdd(&cursor[d4.x], 1);
            int p1 = atomicAdd(&cursor[d4.y], 1);
            int p2 = atomicAdd(&cursor[d4.z], 1);
            int p3 = atomicAdd(&cursor[d4.w], 1);
            ecol[p0] = s4.x;
            ecol[p1] = s4.y;
            ecol[p2] = s4.z;
            ecol[p3] = s4.w;
        } else {
            for (int k = e; k < E && k >= 0; ++k) {
                int pos = atomicAdd(&cursor[dst[k]], 1);
                ecol[pos] = src[k];
            }
        }
        return;
    }
    // ---------------- GEMM 64->64 tile ----------------
    int row0 = (blockIdx.x - PLACE_BLOCKS) * 64;
    for (int i = threadIdx.x; i < 64 * 64; i += 256) sW[i] = W[i];
    for (int i4 = threadIdx.x; i4 < 64 * 16; i4 += 256) {
        int r = i4 >> 4, c4 = i4 & 15;
        int gr = row0 + r;
        float4 v = make_float4(0.f, 0.f, 0.f, 0.f);
        if (gr < N) v = *(const float4*)(X + (long)gr * 64 + c4 * 4);
        *(float4*)&sX[r][c4 * 4] = v;
    }
    __syncthreads();

    int ty = threadIdx.x >> 4, tx = threadIdx.x & 15;
    int r0 = ty * 4, c0 = tx * 4;
    float4 acc0 = make_float4(0.f, 0.f, 0.f, 0.f);
    float4 acc1 = acc0, acc2 = acc0, acc3 = acc0;

#pragma unroll 1
    for (int k = 0; k < 64; k += 4) {
        float4 a0 = *(const float4*)&sX[r0 + 0][k];
        float4 a1 = *(const float4*)&sX[r0 + 1][k];
        float4 a2 = *(const float4*)&sX[r0 + 2][k];
        float4 a3 = *(const float4*)&sX[r0 + 3][k];
        float4 b0 = *(const float4*)&sW[(k + 0) * 64 + c0];
        float4 b1 = *(const float4*)&sW[(k + 1) * 64 + c0];
        float4 b2 = *(const float4*)&sW[(k + 2) * 64 + c0];
        float4 b3 = *(const float4*)&sW[(k + 3) * 64 + c0];
        acc0.x += a0.x*b0.x + a0.y*b1.x + a0.z*b2.x + a0.w*b3.x;
        acc0.y += a0.x*b0.y + a0.y*b1.y + a0.z*b2.y + a0.w*b3.y;
        acc0.z += a0.x*b0.z + a0.y*b1.z + a0.z*b2.z + a0.w*b3.z;
        acc0.w += a0.x*b0.w + a0.y*b1.w + a0.z*b2.w + a0.w*b3.w;
        acc1.x += a1.x*b0.x + a1.y*b1.x + a1.z*b2.x + a1.w*b3.x;
        acc1.y += a1.x*b0.y + a1.y*b1.y + a1.z*b2.y + a1.w*b3.y;
        acc1.z += a1.x*b0.z + a1.y*b1.z + a1.z*b2.z + a1.w*b3.z;
        acc1.w += a1.x*b0.w + a1.y*b1.w + a1.z*b2.w + a1.w*b3.w;
        acc2.x += a2.x*b0.x + a2.y*b1.x + a2.z*b2.x + a2.w*b3.x;
        acc2.y += a2.x*b0.y + a2.y*b1.y + a2.z*b2.y + a2.w*b3.y;
        acc2.z += a2.x*b0.z + a2.y*b1.z + a2.z*b2.z + a2.w*b3.z;
        acc2.w += a2.x*b0.w + a2.y*b1.w + a2.z*b2.w + a2.w*b3.w;
        acc3.x += a3.x*b0.x + a3.y*b1.x + a3.z*b2.x + a3.w*b3.x;
        acc3.y += a3.x*b0.y + a3.y*b1.y + a3.z*b2.y + a3.w*b3.y;
        acc3.z += a3.x*b0.z + a3.y*b1.z + a3.z*b2.z + a3.w*b3.z;
        acc3.w += a3.x*b0.w + a3.y*b1.w + a3.z*b2.w + a3.w*b3.w;
    }
    int gr = row0 + r0;
    if (gr + 0 < N) *(float4*)(H + (long)(gr + 0) * 64 + c0) = acc0;
    if (gr + 1 < N) *(float4*)(H + (long)(gr + 1) * 64 + c0) = acc1;
    if (gr + 2 < N) *(float4*)(H + (long)(gr + 2) * 64 + c0) = acc2;
    if (gr + 3 < N) *(float4*)(H + (long)(gr + 3) * 64 + c0) = acc3;
}

// ---------------- GEMM 64->32: H[N,32] = X[N,64] @ W[64,32] ----------------
__global__ __launch_bounds__(256, 2)
void k_gemm32(const float* __restrict__ X, const float* __restrict__ W,
              float* __restrict__ H) {
    __shared__ float sX[64][68];
    __shared__ float sW[64 * 32];
    int row0 = blockIdx.x * 64;
    for (int i = threadIdx.x; i < 64 * 32; i += 256) sW[i] = W[i];
    for (int i4 = threadIdx.x; i4 < 64 * 16; i4 += 256) {
        int r = i4 >> 4, c4 = i4 & 15;
        int gr = row0 + r;
        float4 v = make_float4(0.f, 0.f, 0.f, 0.f);
        if (gr < N) v = *(const float4*)(X + (long)gr * 64 + c4 * 4);
        *(float4*)&sX[r][c4 * 4] = v;
    }
    __syncthreads();

    int ty = threadIdx.x >> 4, tx = threadIdx.x & 15;
    int r0 = ty * 4, c0 = tx * 2;
    float2 acc0 = make_float2(0.f, 0.f);
    float2 acc1 = acc0, acc2 = acc0, acc3 = acc0;

#pragma unroll 1
    for (int k = 0; k < 64; k += 4) {
        float4 a0 = *(const float4*)&sX[r0 + 0][k];
        float4 a1 = *(const float4*)&sX[r0 + 1][k];
        float4 a2 = *(const float4*)&sX[r0 + 2][k];
        float4 a3 = *(const float4*)&sX[r0 + 3][k];
        float2 b0 = *(const float2*)&sW[(k + 0) * 32 + c0];
        float2 b1 = *(const float2*)&sW[(k + 1) * 32 + c0];
        float2 b2 = *(const float2*)&sW[(k + 2) * 32 + c0];
        float2 b3 = *(const float2*)&sW[(k + 3) * 32 + c0];
        acc0.x += a0.x*b0.x + a0.y*b1.x + a0.z*b2.x + a0.w*b3.x;
        acc0.y += a0.x*b0.y + a0.y*b1.y + a0.z*b2.y + a0.w*b3.y;
        acc1.x += a1.x*b0.x + a1.y*b1.x + a1.z*b2.x + a1.w*b3.x;
        acc1.y += a1.x*b0.y + a1.y*b1.y + a1.z*b2.y + a1.w*b3.y;
        acc2.x += a2.x*b0.x + a2.y*b1.x + a2.z*b2.x + a2.w*b3.x;
        acc2.y += a2.x*b0.y + a2.y*b1.y + a2.z*b2.y + a2.w*b3.y;
        acc3.x += a3.x*b0.x + a3.y*b1.x + a3.z*b2.x + a3.w*b3.x;
        acc3.y += a3.x*b0.y + a3.y*b1.y + a3.z*b2.y + a3.w*b3.y;
    }
    int gr = row0 + r0;
    if (gr + 0 < N) *(float2*)(H + (long)(gr + 0) * 32 + c0) = acc0;
    if (gr + 1 < N) *(float2*)(H + (long)(gr + 1) * 32 + c0) = acc1;
    if (gr + 2 < N) *(float2*)(H + (long)(gr + 2) * 32 + c0) = acc2;
    if (gr + 3 < N) *(float2*)(H + (long)(gr + 3) * 32 + c0) = acc3;
}

// ---------------- gather layer 1 (C=64): one wave per node ----------------
// lane = g*16 + q : g = edge slot group (0..3), q = channel quarter (float4)
// All __shfl ops execute with FULL exec mask; lanes >= cnt hold se=0,we=0.
__global__ void k_gather1(const float* __restrict__ h1, const float* __restrict__ dis,
                          const int* __restrict__ rowptr, const int* __restrict__ deg,
                          const int* __restrict__ ecol,
                          const float* __restrict__ b1, float* __restrict__ agg1) {
    int node = (blockIdx.x << 2) + (threadIdx.x >> 6);
    int lane = threadIdx.x & 63;
    if (node >= N) return;                 // wave-uniform (N % 4 == 0)
    int q = lane & 15;
    int g = lane >> 4;
    int start = rowptr[node];
    int dgr = deg[node];
    float di = dis[node];
    float4 acc = make_float4(0.f, 0.f, 0.f, 0.f);

    for (int base = 0; base < dgr; base += 64) {
        int cnt = min(dgr - base, 64);
        int se = 0; float we = 0.f;
        if (lane < cnt) { se = ecol[start + base + lane]; we = dis[se]; }
        for (int j = 0; j < cnt; j += 8) {
            int s0 = __shfl(se, j + g);       float w0 = __shfl(we, j + g);
            int s1 = __shfl(se, j + 4 + g);   float w1 = __shfl(we, j + 4 + g);
            float4 v0 = *(const float4*)(h1 + ((long)s0 << 6) + q * 4);
            float4 v1 = *(const float4*)(h1 + ((long)s1 << 6) + q * 4);
            acc.x += w0 * v0.x + w1 * v1.x;
            acc.y += w0 * v0.y + w1 * v1.y;
            acc.z += w0 * v0.z + w1 * v1.z;
            acc.w += w0 * v0.w + w1 * v1.w;
        }
    }
#pragma unroll
    for (int off = 16; off <= 32; off <<= 1) {
        acc.x += __shfl_xor(acc.x, off);
        acc.y += __shfl_xor(acc.y, off);
        acc.z += __shfl_xor(acc.z, off);
        acc.w += __shfl_xor(acc.w, off);
    }
    if (g == 0) {
        float4 hv = *(const float4*)(h1 + ((long)node << 6) + q * 4);
        float4 bb = *(const float4*)(b1 + q * 4);
        float4 r;
        r.x = fmaxf(di * (acc.x + di * hv.x) + bb.x, 0.f);
        r.y = fmaxf(di * (acc.y + di * hv.y) + bb.y, 0.f);
        r.z = fmaxf(di * (acc.z + di * hv.z) + bb.z, 0.f);
        r.w = fmaxf(di * (acc.w + di * hv.w) + bb.w, 0.f);
        *(float4*)(agg1 + ((long)node << 6) + q * 4) = r;
    }
}

// ---------------- gather layer 2 (C=32) + log_softmax: one wave per node ------
__global__ void k_gather2(const float* __restrict__ h2, const float* __restrict__ dis,
                          const int* __restrict__ rowptr, const int* __restrict__ deg,
                          const int* __restrict__ ecol,
                          const float* __restrict__ b2, float* __restrict__ out) {
    int node = (blockIdx.x << 2) + (threadIdx.x >> 6);
    int lane = threadIdx.x & 63;
    if (node >= N) return;
    int q = lane & 7;
    int g = lane >> 3;
    int start = rowptr[node];
    int dgr = deg[node];
    float di = dis[node];
    float4 acc = make_float4(0.f, 0.f, 0.f, 0.f);

    for (int base = 0; base < dgr; base += 64) {
        int cnt = min(dgr - base, 64);
        int se = 0; float we = 0.f;
        if (lane < cnt) { se = ecol[start + base + lane]; we = dis[se]; }
        for (int j = 0; j < cnt; j += 16) {
            int s0 = __shfl(se, j + g);       float w0 = __shfl(we, j + g);
            int s1 = __shfl(se, j + 8 + g);   float w1 = __shfl(we, j + 8 + g);
            float4 v0 = *(const float4*)(h2 + ((long)s0 << 5) + q * 4);
            float4 v1 = *(const float4*)(h2 + ((long)s1 << 5) + q * 4);
            acc.x += w0 * v0.x + w1 * v1.x;
            acc.y += w0 * v0.y + w1 * v1.y;
            acc.z += w0 * v0.z + w1 * v1.z;
            acc.w += w0 * v0.w + w1 * v1.w;
        }
    }
#pragma unroll
    for (int off = 8; off <= 32; off <<= 1) {
        acc.x += __shfl_xor(acc.x, off);
        acc.y += __shfl_xor(acc.y, off);
        acc.z += __shfl_xor(acc.z, off);
        acc.w += __shfl_xor(acc.w, off);
    }
    float4 hv = *(const float4*)(h2 + ((long)node << 5) + q * 4);
    float4 bb = *(const float4*)(b2 + q * 4);
    float4 v;
    v.x = di * (acc.x + di * hv.x) + bb.x;
    v.y = di * (acc.y + di * hv.y) + bb.y;
    v.z = di * (acc.z + di * hv.z) + bb.z;
    v.w = di * (acc.w + di * hv.w) + bb.w;
    float m = fmaxf(fmaxf(v.x, v.y), fmaxf(v.z, v.w));
#pragma unroll
    for (int off = 1; off <= 4; off <<= 1) m = fmaxf(m, __shfl_xor(m, off));
    float s = expf(v.x - m) + expf(v.y - m) + expf(v.z - m) + expf(v.w - m);
#pragma unroll
    for (int off = 1; off <= 4; off <<= 1) s += __shfl_xor(s, off);
    float lg = m + logf(s);
    if (g == 0) {
        float4 r;
        r.x = v.x - lg; r.y = v.y - lg; r.z = v.z - lg; r.w = v.w - lg;
        *(float4*)(out + ((long)node << 5) + q * 4) = r;
    }
}

extern "C" void kernel_launch(void* const* d_in, const int* in_sizes, int n_in,
                              void* d_out, int out_size, void* d_ws, size_t ws_size,
                              hipStream_t stream) {
    const float* x  = (const float*)d_in[0];
    const int*   ei = (const int*)d_in[1];
    const float* W1 = (const float*)d_in[2];
    const float* b1 = (const float*)d_in[3];
    const float* W2 = (const float*)d_in[4];
    const float* b2 = (const float*)d_in[5];
    float* out = (float*)d_out;

    const int* src = ei;
    const int* dst = ei + E;

    char* w = (char*)d_ws;
    int*   deg    = (int*)(w + 0);
    float* dis    = (float*)(w + (512u << 10));
    int*   rowptr = (int*)(w + (1024u << 10));
    int*   cursor = (int*)(w + (1536u << 10));
    int*   bsum   = (int*)(w + (2048u << 10));
    int*   ecol   = (int*)(w + (2560u << 10));
    float* h1     = (float*)(w + (10240u << 10));  // 25.6 MB (reused as h2)
    float* agg1   = (float*)(w + (36864u << 10));  // 25.6 MB
    float* h2     = h1;                            // h1 dead after gather1

    hipMemsetAsync(deg, 0, (size_t)N * 4, stream);
    k_degree<<<(E / 4 + 255) / 256, 256, 0, stream>>>(dst, deg);

    k_scanA<<<NB, 256, 0, stream>>>(deg, rowptr, bsum);
    k_scanC<<<(N + 255) / 256, 256, 0, stream>>>(rowptr, bsum, cursor, deg, dis);

    // fused: place (first 782 blocks) overlapped with gemm64 (next 1563 blocks)
    k_place_gemm64<<<PLACE_BLOCKS + GEMM_BLOCKS, 256, 0, stream>>>(
        src, dst, cursor, ecol, x, W1, h1);

    k_gather1<<<(N + 3) / 4, 256, 0, stream>>>(h1, dis, rowptr, deg, ecol, b1, agg1);

    k_gemm32<<<(N + 63) / 64, 256, 0, stream>>>(agg1, W2, h2);
    k_gather2<<<(N + 3) / 4, 256, 0, stream>>>(h2, dis, rowptr, deg, ecol, b2, out);
}

// Round 12
// 188.019 us; speedup vs baseline: 2.5540x; 1.1306x over previous
//
#include <hip/hip_runtime.h>

// GCN 2-layer via CSR gather. R12: (a) XCD-partitioned place/degree — block
// b&7 ~ XCD id, processes only dst-partition b&7, so cursor atomics + ecol
// stores are XCD-L2-local (kills the 51MB write-through scatter); (b) h1 in
// bf16 (RNE) — halves gather1's random-row L2 fill and gemm64's h1 write.
// GEMM k-loops kept ROLLED (#pragma unroll 1): full unroll -> 512 VGPR spill storm.
constexpr int N  = 100000;
constexpr int E  = 800000;
constexpr int CHUNK = 1024;
constexpr int NB = (N + CHUNK - 1) / CHUNK;     // 98 scan blocks
constexpr int PSIZE = 12500;                    // dst-partition width (N/8)
constexpr int GRPS  = 96;                       // edge-slice groups
constexpr int EPG   = 8336;                     // ceil(E/GRPS), multiple of 16
constexpr int PLACE_BLOCKS = GRPS * 8;          // 768
constexpr int GEMM_BLOCKS  = (N + 63) / 64;     // 1563

__device__ __forceinline__ unsigned short f2bf(float f) {
    unsigned u = __float_as_uint(f);
    unsigned r = (u + 0x7FFFu + ((u >> 16) & 1u)) >> 16;   // RNE
    return (unsigned short)r;
}
__device__ __forceinline__ float bf_lo(unsigned u) { return __uint_as_float(u << 16); }
__device__ __forceinline__ float bf_hi(unsigned u) { return __uint_as_float(u & 0xffff0000u); }

// -------- degree: XCD-partitioned (block b&7 handles dst/PSIZE == b&7) --------
__global__ void k_degree(const int* __restrict__ dst, int* __restrict__ deg) {
    int part = blockIdx.x & 7;
    int grp  = blockIdx.x >> 3;
    int lo = grp * EPG;
    int hi = min(lo + EPG, E);
    for (int e = lo + (threadIdx.x << 2); e < hi; e += 1024) {
        int4 d4 = *(const int4*)(dst + e);
        if (d4.x / PSIZE == part) atomicAdd(&deg[d4.x], 1);
        if (d4.y / PSIZE == part) atomicAdd(&deg[d4.y], 1);
        if (d4.z / PSIZE == part) atomicAdd(&deg[d4.z], 1);
        if (d4.w / PSIZE == part) atomicAdd(&deg[d4.w], 1);
    }
}

// ---------------- exclusive scan of deg -> rowptr ----------------
__global__ void k_scanA(const int* __restrict__ deg, int* __restrict__ rowptr,
                        int* __restrict__ bsum) {
    __shared__ int a[2][256];
    int b = blockIdx.x, t = threadIdx.x;
    int base = b * CHUNK + t * 4;
    int v[4];
#pragma unroll
    for (int k = 0; k < 4; ++k) v[k] = (base + k < N) ? deg[base + k] : 0;
    int mysum = v[0] + v[1] + v[2] + v[3];
    a[0][t] = mysum;
    __syncthreads();
    int pin = 0;
    for (int off = 1; off < 256; off <<= 1) {
        int x = a[pin][t];
        if (t >= off) x += a[pin][t - off];
        a[pin ^ 1][t] = x;
        __syncthreads();
        pin ^= 1;
    }
    int incl = a[pin][t];
    int run = incl - mysum;
#pragma unroll
    for (int k = 0; k < 4; ++k) {
        if (base + k < N) rowptr[base + k] = run;
        run += v[k];
    }
    if (t == 255) bsum[b] = incl;
}

// scanC: adds global chunk offset (computed in-block from bsum), writes cursor + dis
__global__ void k_scanC(int* __restrict__ rowptr, const int* __restrict__ bsum,
                        int* __restrict__ cursor, const int* __restrict__ deg,
                        float* __restrict__ dis) {
    __shared__ int s_off;
    int cid = blockIdx.x >> 2;
    if (threadIdx.x == 0) {
        int run = 0;
        for (int i = 0; i < cid; ++i) run += bsum[i];
        s_off = run;
    }
    __syncthreads();
    int i = blockIdx.x * blockDim.x + threadIdx.x;
    if (i < N) {
        int r = rowptr[i] + s_off;
        rowptr[i] = r;
        cursor[i] = r;
        dis[i] = rsqrtf((float)(deg[i] + 1));   // +1 self-loop
    }
}

// -------- FUSED: blocks [0,PLACE_BLOCKS) = partitioned place; rest = GEMM64 --------
// place: block (grp = b>>3, part = b&7): stream slice grp, keep dst-partition part.
__global__ __launch_bounds__(256, 2)
void k_place_gemm64(const int* __restrict__ src, const int* __restrict__ dst,
                    int* __restrict__ cursor, int* __restrict__ ecol,
                    const float* __restrict__ X, const float* __restrict__ W,
                    unsigned short* __restrict__ Hb) {
    __shared__ float sX[64][68];
    __shared__ float sW[64 * 64];
    if (blockIdx.x < PLACE_BLOCKS) {
        int part = blockIdx.x & 7;
        int grp  = blockIdx.x >> 3;
        int lo = grp * EPG;
        int hi = min(lo + EPG, E);
        for (int e = lo + (threadIdx.x << 2); e < hi; e += 1024) {
            int4 s4 = *(const int4*)(src + e);
            int4 d4 = *(const int4*)(dst + e);
            if (d4.x / PSIZE == part) { int p = atomicAdd(&cursor[d4.x], 1); ecol[p] = s4.x; }
            if (d4.y / PSIZE == part) { int p = atomicAdd(&cursor[d4.y], 1); ecol[p] = s4.y; }
            if (d4.z / PSIZE == part) { int p = atomicAdd(&cursor[d4.z], 1); ecol[p] = s4.z; }
            if (d4.w / PSIZE == part) { int p = atomicAdd(&cursor[d4.w], 1); ecol[p] = s4.w; }
        }
        return;
    }
    // ---------------- GEMM 64->64 tile, bf16 output ----------------
    int row0 = (blockIdx.x - PLACE_BLOCKS) * 64;
    for (int i = threadIdx.x; i < 64 * 64; i += 256) sW[i] = W[i];
    for (int i4 = threadIdx.x; i4 < 64 * 16; i4 += 256) {
        int r = i4 >> 4, c4 = i4 & 15;
        int gr = row0 + r;
        float4 v = make_float4(0.f, 0.f, 0.f, 0.f);
        if (gr < N) v = *(const float4*)(X + (long)gr * 64 + c4 * 4);
        *(float4*)&sX[r][c4 * 4] = v;
    }
    __syncthreads();

    int ty = threadIdx.x >> 4, tx = threadIdx.x & 15;
    int r0 = ty * 4, c0 = tx * 4;
    float4 acc0 = make_float4(0.f, 0.f, 0.f, 0.f);
    float4 acc1 = acc0, acc2 = acc0, acc3 = acc0;

#pragma unroll 1
    for (int k = 0; k < 64; k += 4) {
        float4 a0 = *(const float4*)&sX[r0 + 0][k];
        float4 a1 = *(const float4*)&sX[r0 + 1][k];
        float4 a2 = *(const float4*)&sX[r0 + 2][k];
        float4 a3 = *(const float4*)&sX[r0 + 3][k];
        float4 b0 = *(const float4*)&sW[(k + 0) * 64 + c0];
        float4 b1 = *(const float4*)&sW[(k + 1) * 64 + c0];
        float4 b2 = *(const float4*)&sW[(k + 2) * 64 + c0];
        float4 b3 = *(const float4*)&sW[(k + 3) * 64 + c0];
        acc0.x += a0.x*b0.x + a0.y*b1.x + a0.z*b2.x + a0.w*b3.x;
        acc0.y += a0.x*b0.y + a0.y*b1.y + a0.z*b2.y + a0.w*b3.y;
        acc0.z += a0.x*b0.z + a0.y*b1.z + a0.z*b2.z + a0.w*b3.z;
        acc0.w += a0.x*b0.w + a0.y*b1.w + a0.z*b2.w + a0.w*b3.w;
        acc1.x += a1.x*b0.x + a1.y*b1.x + a1.z*b2.x + a1.w*b3.x;
        acc1.y += a1.x*b0.y + a1.y*b1.y + a1.z*b2.y + a1.w*b3.y;
        acc1.z += a1.x*b0.z + a1.y*b1.z + a1.z*b2.z + a1.w*b3.z;
        acc1.w += a1.x*b0.w + a1.y*b1.w + a1.z*b2.w + a1.w*b3.w;
        acc2.x += a2.x*b0.x + a2.y*b1.x + a2.z*b2.x + a2.w*b3.x;
        acc2.y += a2.x*b0.y + a2.y*b1.y + a2.z*b2.y + a2.w*b3.y;
        acc2.z += a2.x*b0.z + a2.y*b1.z + a2.z*b2.z + a2.w*b3.z;
        acc2.w += a2.x*b0.w + a2.y*b1.w + a2.z*b2.w + a2.w*b3.w;
        acc3.x += a3.x*b0.x + a3.y*b1.x + a3.z*b2.x + a3.w*b3.x;
        acc3.y += a3.x*b0.y + a3.y*b1.y + a3.z*b2.y + a3.w*b3.y;
        acc3.z += a3.x*b0.z + a3.y*b1.z + a3.z*b2.z + a3.w*b3.z;
        acc3.w += a3.x*b0.w + a3.y*b1.w + a3.z*b2.w + a3.w*b3.w;
    }
    int gr = row0 + r0;
    if (gr + 0 < N) {
        ushort4 o; o.x=f2bf(acc0.x); o.y=f2bf(acc0.y); o.z=f2bf(acc0.z); o.w=f2bf(acc0.w);
        *(ushort4*)(Hb + (long)(gr + 0) * 64 + c0) = o;
    }
    if (gr + 1 < N) {
        ushort4 o; o.x=f2bf(acc1.x); o.y=f2bf(acc1.y); o.z=f2bf(acc1.z); o.w=f2bf(acc1.w);
        *(ushort4*)(Hb + (long)(gr + 1) * 64 + c0) = o;
    }
    if (gr + 2 < N) {
        ushort4 o; o.x=f2bf(acc2.x); o.y=f2bf(acc2.y); o.z=f2bf(acc2.z); o.w=f2bf(acc2.w);
        *(ushort4*)(Hb + (long)(gr + 2) * 64 + c0) = o;
    }
    if (gr + 3 < N) {
        ushort4 o; o.x=f2bf(acc3.x); o.y=f2bf(acc3.y); o.z=f2bf(acc3.z); o.w=f2bf(acc3.w);
        *(ushort4*)(Hb + (long)(gr + 3) * 64 + c0) = o;
    }
}

// ---------------- GEMM 64->32: H[N,32] = X[N,64] @ W[64,32] (fp32) ------------
__global__ __launch_bounds__(256, 2)
void k_gemm32(const float* __restrict__ X, const float* __restrict__ W,
              float* __restrict__ H) {
    __shared__ float sX[64][68];
    __shared__ float sW[64 * 32];
    int row0 = blockIdx.x * 64;
    for (int i = threadIdx.x; i < 64 * 32; i += 256) sW[i] = W[i];
    for (int i4 = threadIdx.x; i4 < 64 * 16; i4 += 256) {
        int r = i4 >> 4, c4 = i4 & 15;
        int gr = row0 + r;
        float4 v = make_float4(0.f, 0.f, 0.f, 0.f);
        if (gr < N) v = *(const float4*)(X + (long)gr * 64 + c4 * 4);
        *(float4*)&sX[r][c4 * 4] = v;
    }
    __syncthreads();

    int ty = threadIdx.x >> 4, tx = threadIdx.x & 15;
    int r0 = ty * 4, c0 = tx * 2;
    float2 acc0 = make_float2(0.f, 0.f);
    float2 acc1 = acc0, acc2 = acc0, acc3 = acc0;

#pragma unroll 1
    for (int k = 0; k < 64; k += 4) {
        float4 a0 = *(const float4*)&sX[r0 + 0][k];
        float4 a1 = *(const float4*)&sX[r0 + 1][k];
        float4 a2 = *(const float4*)&sX[r0 + 2][k];
        float4 a3 = *(const float4*)&sX[r0 + 3][k];
        float2 b0 = *(const float2*)&sW[(k + 0) * 32 + c0];
        float2 b1 = *(const float2*)&sW[(k + 1) * 32 + c0];
        float2 b2 = *(const float2*)&sW[(k + 2) * 32 + c0];
        float2 b3 = *(const float2*)&sW[(k + 3) * 32 + c0];
        acc0.x += a0.x*b0.x + a0.y*b1.x + a0.z*b2.x + a0.w*b3.x;
        acc0.y += a0.x*b0.y + a0.y*b1.y + a0.z*b2.y + a0.w*b3.y;
        acc1.x += a1.x*b0.x + a1.y*b1.x + a1.z*b2.x + a1.w*b3.x;
        acc1.y += a1.x*b0.y + a1.y*b1.y + a1.z*b2.y + a1.w*b3.y;
        acc2.x += a2.x*b0.x + a2.y*b1.x + a2.z*b2.x + a2.w*b3.x;
        acc2.y += a2.x*b0.y + a2.y*b1.y + a2.z*b2.y + a2.w*b3.y;
        acc3.x += a3.x*b0.x + a3.y*b1.x + a3.z*b2.x + a3.w*b3.x;
        acc3.y += a3.x*b0.y + a3.y*b1.y + a3.z*b2.y + a3.w*b3.y;
    }
    int gr = row0 + r0;
    if (gr + 0 < N) *(float2*)(H + (long)(gr + 0) * 32 + c0) = acc0;
    if (gr + 1 < N) *(float2*)(H + (long)(gr + 1) * 32 + c0) = acc1;
    if (gr + 2 < N) *(float2*)(H + (long)(gr + 2) * 32 + c0) = acc2;
    if (gr + 3 < N) *(float2*)(H + (long)(gr + 3) * 32 + c0) = acc3;
}

// ---------------- gather layer 1 (C=64, bf16 h1): one wave per node ------------
// lane = g*16 + q : g = edge slot group (0..3), q = channel quarter (4 bf16 = 8B)
__global__ void k_gather1(const unsigned short* __restrict__ h1b,
                          const float* __restrict__ dis,
                          const int* __restrict__ rowptr, const int* __restrict__ deg,
                          const int* __restrict__ ecol,
                          const float* __restrict__ b1, float* __restrict__ agg1) {
    int node = (blockIdx.x << 2) + (threadIdx.x >> 6);
    int lane = threadIdx.x & 63;
    if (node >= N) return;                 // wave-uniform (N % 4 == 0)
    int q = lane & 15;
    int g = lane >> 4;
    int start = rowptr[node];
    int dgr = deg[node];
    float di = dis[node];
    float4 acc = make_float4(0.f, 0.f, 0.f, 0.f);

    for (int base = 0; base < dgr; base += 64) {
        int cnt = min(dgr - base, 64);
        int se = 0; float we = 0.f;
        if (lane < cnt) { se = ecol[start + base + lane]; we = dis[se]; }
        for (int j = 0; j < cnt; j += 8) {
            int s0 = __shfl(se, j + g);       float w0 = __shfl(we, j + g);
            int s1 = __shfl(se, j + 4 + g);   float w1 = __shfl(we, j + 4 + g);
            uint2 u0 = *(const uint2*)(h1b + ((long)s0 << 6) + (q << 2));
            uint2 u1 = *(const uint2*)(h1b + ((long)s1 << 6) + (q << 2));
            acc.x += w0 * bf_lo(u0.x) + w1 * bf_lo(u1.x);
            acc.y += w0 * bf_hi(u0.x) + w1 * bf_hi(u1.x);
            acc.z += w0 * bf_lo(u0.y) + w1 * bf_lo(u1.y);
            acc.w += w0 * bf_hi(u0.y) + w1 * bf_hi(u1.y);
        }
    }
#pragma unroll
    for (int off = 16; off <= 32; off <<= 1) {
        acc.x += __shfl_xor(acc.x, off);
        acc.y += __shfl_xor(acc.y, off);
        acc.z += __shfl_xor(acc.z, off);
        acc.w += __shfl_xor(acc.w, off);
    }
    if (g == 0) {
        uint2 uh = *(const uint2*)(h1b + ((long)node << 6) + (q << 2));
        float4 bb = *(const float4*)(b1 + q * 4);
        float4 r;
        r.x = fmaxf(di * (acc.x + di * bf_lo(uh.x)) + bb.x, 0.f);
        r.y = fmaxf(di * (acc.y + di * bf_hi(uh.x)) + bb.y, 0.f);
        r.z = fmaxf(di * (acc.z + di * bf_lo(uh.y)) + bb.z, 0.f);
        r.w = fmaxf(di * (acc.w + di * bf_hi(uh.y)) + bb.w, 0.f);
        *(float4*)(agg1 + ((long)node << 6) + q * 4) = r;
    }
}

// ---------------- gather layer 2 (C=32, fp32 h2) + log_softmax ----------------
__global__ void k_gather2(const float* __restrict__ h2, const float* __restrict__ dis,
                          const int* __restrict__ rowptr, const int* __restrict__ deg,
                          const int* __restrict__ ecol,
                          const float* __restrict__ b2, float* __restrict__ out) {
    int node = (blockIdx.x << 2) + (threadIdx.x >> 6);
    int lane = threadIdx.x & 63;
    if (node >= N) return;
    int q = lane & 7;
    int g = lane >> 3;
    int start = rowptr[node];
    int dgr = deg[node];
    float di = dis[node];
    float4 acc = make_float4(0.f, 0.f, 0.f, 0.f);

    for (int base = 0; base < dgr; base += 64) {
        int cnt = min(dgr - base, 64);
        int se = 0; float we = 0.f;
        if (lane < cnt) { se = ecol[start + base + lane]; we = dis[se]; }
        for (int j = 0; j < cnt; j += 16) {
            int s0 = __shfl(se, j + g);       float w0 = __shfl(we, j + g);
            int s1 = __shfl(se, j + 8 + g);   float w1 = __shfl(we, j + 8 + g);
            float4 v0 = *(const float4*)(h2 + ((long)s0 << 5) + q * 4);
            float4 v1 = *(const float4*)(h2 + ((long)s1 << 5) + q * 4);
            acc.x += w0 * v0.x + w1 * v1.x;
            acc.y += w0 * v0.y + w1 * v1.y;
            acc.z += w0 * v0.z + w1 * v1.z;
            acc.w += w0 * v0.w + w1 * v1.w;
        }
    }
#pragma unroll
    for (int off = 8; off <= 32; off <<= 1) {
        acc.x += __shfl_xor(acc.x, off);
        acc.y += __shfl_xor(acc.y, off);
        acc.z += __shfl_xor(acc.z, off);
        acc.w += __shfl_xor(acc.w, off);
    }
    float4 hv = *(const float4*)(h2 + ((long)node << 5) + q * 4);
    float4 bb = *(const float4*)(b2 + q * 4);
    float4 v;
    v.x = di * (acc.x + di * hv.x) + bb.x;
    v.y = di * (acc.y + di * hv.y) + bb.y;
    v.z = di * (acc.z + di * hv.z) + bb.z;
    v.w = di * (acc.w + di * hv.w) + bb.w;
    float m = fmaxf(fmaxf(v.x, v.y), fmaxf(v.z, v.w));
#pragma unroll
    for (int off = 1; off <= 4; off <<= 1) m = fmaxf(m, __shfl_xor(m, off));
    float s = expf(v.x - m) + expf(v.y - m) + expf(v.z - m) + expf(v.w - m);
#pragma unroll
    for (int off = 1; off <= 4; off <<= 1) s += __shfl_xor(s, off);
    float lg = m + logf(s);
    if (g == 0) {
        float4 r;
        r.x = v.x - lg; r.y = v.y - lg; r.z = v.z - lg; r.w = v.w - lg;
        *(float4*)(out + ((long)node << 5) + q * 4) = r;
    }
}

extern "C" void kernel_launch(void* const* d_in, const int* in_sizes, int n_in,
                              void* d_out, int out_size, void* d_ws, size_t ws_size,
                              hipStream_t stream) {
    const float* x  = (const float*)d_in[0];
    const int*   ei = (const int*)d_in[1];
    const float* W1 = (const float*)d_in[2];
    const float* b1 = (const float*)d_in[3];
    const float* W2 = (const float*)d_in[4];
    const float* b2 = (const float*)d_in[5];
    float* out = (float*)d_out;

    const int* src = ei;
    const int* dst = ei + E;

    char* w = (char*)d_ws;
    int*   deg    = (int*)(w + 0);
    float* dis    = (float*)(w + (512u << 10));
    int*   rowptr = (int*)(w + (1024u << 10));
    int*   cursor = (int*)(w + (1536u << 10));
    int*   bsum   = (int*)(w + (2048u << 10));
    int*   ecol   = (int*)(w + (2560u << 10));                      // 3.2 MB
    unsigned short* h1b = (unsigned short*)(w + (10240u << 10));    // 12.8 MB bf16
    float* h2     = (float*)(w + (24576u << 10));                   // 12.8 MB fp32
    float* agg1   = (float*)(w + (38912u << 10));                   // 25.6 MB fp32

    hipMemsetAsync(deg, 0, (size_t)N * 4, stream);
    k_degree<<<GRPS * 8, 256, 0, stream>>>(dst, deg);

    k_scanA<<<NB, 256, 0, stream>>>(deg, rowptr, bsum);
    k_scanC<<<(N + 255) / 256, 256, 0, stream>>>(rowptr, bsum, cursor, deg, dis);

    // fused: partitioned place (768 blocks) overlapped with gemm64 (1563 blocks)
    k_place_gemm64<<<PLACE_BLOCKS + GEMM_BLOCKS, 256, 0, stream>>>(
        src, dst, cursor, ecol, x, W1, h1b);

    k_gather1<<<(N + 3) / 4, 256, 0, stream>>>(h1b, dis, rowptr, deg, ecol, b1, agg1);

    k_gemm32<<<(N + 63) / 64, 256, 0, stream>>>(agg1, W2, h2);
    k_gather2<<<(N + 3) / 4, 256, 0, stream>>>(h2, dis, rowptr, deg, ecol, b2, out);
}

// Round 13
// 185.755 us; speedup vs baseline: 2.5851x; 1.0122x over previous
//
#include <hip/hip_runtime.h>

// GCN 2-layer via CSR gather. R13 = R12 + bf16 for agg1 and h2 (all large
// intermediates now bf16 storage, fp32 compute). XCD-partitioned place/degree,
// fused place+gemm64, ROLLED GEMM k-loops (full unroll -> 512 VGPR spill storm).
constexpr int N  = 100000;
constexpr int E  = 800000;
constexpr int CHUNK = 1024;
constexpr int NB = (N + CHUNK - 1) / CHUNK;     // 98 scan blocks
constexpr int PSIZE = 12500;                    // dst-partition width (N/8)
constexpr int GRPS  = 96;                       // edge-slice groups
constexpr int EPG   = 8336;                     // ceil(E/GRPS), multiple of 16
constexpr int PLACE_BLOCKS = GRPS * 8;          // 768
constexpr int GEMM_BLOCKS  = (N + 63) / 64;     // 1563

__device__ __forceinline__ unsigned short f2bf(float f) {
    unsigned u = __float_as_uint(f);
    unsigned r = (u + 0x7FFFu + ((u >> 16) & 1u)) >> 16;   // RNE
    return (unsigned short)r;
}
__device__ __forceinline__ float bf_lo(unsigned u) { return __uint_as_float(u << 16); }
__device__ __forceinline__ float bf_hi(unsigned u) { return __uint_as_float(u & 0xffff0000u); }

// -------- degree: XCD-partitioned (block b&7 handles dst/PSIZE == b&7) --------
__global__ void k_degree(const int* __restrict__ dst, int* __restrict__ deg) {
    int part = blockIdx.x & 7;
    int grp  = blockIdx.x >> 3;
    int lo = grp * EPG;
    int hi = min(lo + EPG, E);
    for (int e = lo + (threadIdx.x << 2); e < hi; e += 1024) {
        int4 d4 = *(const int4*)(dst + e);
        if (d4.x / PSIZE == part) atomicAdd(&deg[d4.x], 1);
        if (d4.y / PSIZE == part) atomicAdd(&deg[d4.y], 1);
        if (d4.z / PSIZE == part) atomicAdd(&deg[d4.z], 1);
        if (d4.w / PSIZE == part) atomicAdd(&deg[d4.w], 1);
    }
}

// ---------------- exclusive scan of deg -> rowptr ----------------
__global__ void k_scanA(const int* __restrict__ deg, int* __restrict__ rowptr,
                        int* __restrict__ bsum) {
    __shared__ int a[2][256];
    int b = blockIdx.x, t = threadIdx.x;
    int base = b * CHUNK + t * 4;
    int v[4];
#pragma unroll
    for (int k = 0; k < 4; ++k) v[k] = (base + k < N) ? deg[base + k] : 0;
    int mysum = v[0] + v[1] + v[2] + v[3];
    a[0][t] = mysum;
    __syncthreads();
    int pin = 0;
    for (int off = 1; off < 256; off <<= 1) {
        int x = a[pin][t];
        if (t >= off) x += a[pin][t - off];
        a[pin ^ 1][t] = x;
        __syncthreads();
        pin ^= 1;
    }
    int incl = a[pin][t];
    int run = incl - mysum;
#pragma unroll
    for (int k = 0; k < 4; ++k) {
        if (base + k < N) rowptr[base + k] = run;
        run += v[k];
    }
    if (t == 255) bsum[b] = incl;
}

// scanC: adds global chunk offset (computed in-block from bsum), writes cursor + dis
__global__ void k_scanC(int* __restrict__ rowptr, const int* __restrict__ bsum,
                        int* __restrict__ cursor, const int* __restrict__ deg,
                        float* __restrict__ dis) {
    __shared__ int s_off;
    int cid = blockIdx.x >> 2;
    if (threadIdx.x == 0) {
        int run = 0;
        for (int i = 0; i < cid; ++i) run += bsum[i];
        s_off = run;
    }
    __syncthreads();
    int i = blockIdx.x * blockDim.x + threadIdx.x;
    if (i < N) {
        int r = rowptr[i] + s_off;
        rowptr[i] = r;
        cursor[i] = r;
        dis[i] = rsqrtf((float)(deg[i] + 1));   // +1 self-loop
    }
}

// -------- FUSED: blocks [0,PLACE_BLOCKS) = partitioned place; rest = GEMM64 --------
__global__ __launch_bounds__(256, 2)
void k_place_gemm64(const int* __restrict__ src, const int* __restrict__ dst,
                    int* __restrict__ cursor, int* __restrict__ ecol,
                    const float* __restrict__ X, const float* __restrict__ W,
                    unsigned short* __restrict__ Hb) {
    __shared__ float sX[64][68];
    __shared__ float sW[64 * 64];
    if (blockIdx.x < PLACE_BLOCKS) {
        int part = blockIdx.x & 7;
        int grp  = blockIdx.x >> 3;
        int lo = grp * EPG;
        int hi = min(lo + EPG, E);
        for (int e = lo + (threadIdx.x << 2); e < hi; e += 1024) {
            int4 s4 = *(const int4*)(src + e);
            int4 d4 = *(const int4*)(dst + e);
            if (d4.x / PSIZE == part) { int p = atomicAdd(&cursor[d4.x], 1); ecol[p] = s4.x; }
            if (d4.y / PSIZE == part) { int p = atomicAdd(&cursor[d4.y], 1); ecol[p] = s4.y; }
            if (d4.z / PSIZE == part) { int p = atomicAdd(&cursor[d4.z], 1); ecol[p] = s4.z; }
            if (d4.w / PSIZE == part) { int p = atomicAdd(&cursor[d4.w], 1); ecol[p] = s4.w; }
        }
        return;
    }
    // ---------------- GEMM 64->64 tile, bf16 output ----------------
    int row0 = (blockIdx.x - PLACE_BLOCKS) * 64;
    for (int i = threadIdx.x; i < 64 * 64; i += 256) sW[i] = W[i];
    for (int i4 = threadIdx.x; i4 < 64 * 16; i4 += 256) {
        int r = i4 >> 4, c4 = i4 & 15;
        int gr = row0 + r;
        float4 v = make_float4(0.f, 0.f, 0.f, 0.f);
        if (gr < N) v = *(const float4*)(X + (long)gr * 64 + c4 * 4);
        *(float4*)&sX[r][c4 * 4] = v;
    }
    __syncthreads();

    int ty = threadIdx.x >> 4, tx = threadIdx.x & 15;
    int r0 = ty * 4, c0 = tx * 4;
    float4 acc0 = make_float4(0.f, 0.f, 0.f, 0.f);
    float4 acc1 = acc0, acc2 = acc0, acc3 = acc0;

#pragma unroll 1
    for (int k = 0; k < 64; k += 4) {
        float4 a0 = *(const float4*)&sX[r0 + 0][k];
        float4 a1 = *(const float4*)&sX[r0 + 1][k];
        float4 a2 = *(const float4*)&sX[r0 + 2][k];
        float4 a3 = *(const float4*)&sX[r0 + 3][k];
        float4 b0 = *(const float4*)&sW[(k + 0) * 64 + c0];
        float4 b1 = *(const float4*)&sW[(k + 1) * 64 + c0];
        float4 b2 = *(const float4*)&sW[(k + 2) * 64 + c0];
        float4 b3 = *(const float4*)&sW[(k + 3) * 64 + c0];
        acc0.x += a0.x*b0.x + a0.y*b1.x + a0.z*b2.x + a0.w*b3.x;
        acc0.y += a0.x*b0.y + a0.y*b1.y + a0.z*b2.y + a0.w*b3.y;
        acc0.z += a0.x*b0.z + a0.y*b1.z + a0.z*b2.z + a0.w*b3.z;
        acc0.w += a0.x*b0.w + a0.y*b1.w + a0.z*b2.w + a0.w*b3.w;
        acc1.x += a1.x*b0.x + a1.y*b1.x + a1.z*b2.x + a1.w*b3.x;
        acc1.y += a1.x*b0.y + a1.y*b1.y + a1.z*b2.y + a1.w*b3.y;
        acc1.z += a1.x*b0.z + a1.y*b1.z + a1.z*b2.z + a1.w*b3.z;
        acc1.w += a1.x*b0.w + a1.y*b1.w + a1.z*b2.w + a1.w*b3.w;
        acc2.x += a2.x*b0.x + a2.y*b1.x + a2.z*b2.x + a2.w*b3.x;
        acc2.y += a2.x*b0.y + a2.y*b1.y + a2.z*b2.y + a2.w*b3.y;
        acc2.z += a2.x*b0.z + a2.y*b1.z + a2.z*b2.z + a2.w*b3.z;
        acc2.w += a2.x*b0.w + a2.y*b1.w + a2.z*b2.w + a2.w*b3.w;
        acc3.x += a3.x*b0.x + a3.y*b1.x + a3.z*b2.x + a3.w*b3.x;
        acc3.y += a3.x*b0.y + a3.y*b1.y + a3.z*b2.y + a3.w*b3.y;
        acc3.z += a3.x*b0.z + a3.y*b1.z + a3.z*b2.z + a3.w*b3.z;
        acc3.w += a3.x*b0.w + a3.y*b1.w + a3.z*b2.w + a3.w*b3.w;
    }
    int gr = row0 + r0;
    if (gr + 0 < N) {
        ushort4 o; o.x=f2bf(acc0.x); o.y=f2bf(acc0.y); o.z=f2bf(acc0.z); o.w=f2bf(acc0.w);
        *(ushort4*)(Hb + (long)(gr + 0) * 64 + c0) = o;
    }
    if (gr + 1 < N) {
        ushort4 o; o.x=f2bf(acc1.x); o.y=f2bf(acc1.y); o.z=f2bf(acc1.z); o.w=f2bf(acc1.w);
        *(ushort4*)(Hb + (long)(gr + 1) * 64 + c0) = o;
    }
    if (gr + 2 < N) {
        ushort4 o; o.x=f2bf(acc2.x); o.y=f2bf(acc2.y); o.z=f2bf(acc2.z); o.w=f2bf(acc2.w);
        *(ushort4*)(Hb + (long)(gr + 2) * 64 + c0) = o;
    }
    if (gr + 3 < N) {
        ushort4 o; o.x=f2bf(acc3.x); o.y=f2bf(acc3.y); o.z=f2bf(acc3.z); o.w=f2bf(acc3.w);
        *(ushort4*)(Hb + (long)(gr + 3) * 64 + c0) = o;
    }
}

// ------- GEMM 64->32: h2b[N,32](bf16) = agg1b[N,64](bf16) @ W[64,32] ---------
__global__ __launch_bounds__(256, 2)
void k_gemm32(const unsigned short* __restrict__ Xb, const float* __restrict__ W,
              unsigned* __restrict__ Hb2) {           // Hb2: 2 bf16 per uint
    __shared__ float sX[64][68];
    __shared__ float sW[64 * 32];
    int row0 = blockIdx.x * 64;
    for (int i = threadIdx.x; i < 64 * 32; i += 256) sW[i] = W[i];
    // stage bf16 X -> fp32 LDS: 8 channels (uint4) per iteration
    for (int i8 = threadIdx.x; i8 < 64 * 8; i8 += 256) {
        int r = i8 >> 3, c8 = i8 & 7;
        int gr = row0 + r;
        uint4 u = make_uint4(0u, 0u, 0u, 0u);
        if (gr < N) u = *(const uint4*)(Xb + (long)gr * 64 + c8 * 8);
        float* sp = &sX[r][c8 * 8];
        sp[0] = bf_lo(u.x); sp[1] = bf_hi(u.x);
        sp[2] = bf_lo(u.y); sp[3] = bf_hi(u.y);
        sp[4] = bf_lo(u.z); sp[5] = bf_hi(u.z);
        sp[6] = bf_lo(u.w); sp[7] = bf_hi(u.w);
    }
    __syncthreads();

    int ty = threadIdx.x >> 4, tx = threadIdx.x & 15;
    int r0 = ty * 4, c0 = tx * 2;
    float2 acc0 = make_float2(0.f, 0.f);
    float2 acc1 = acc0, acc2 = acc0, acc3 = acc0;

#pragma unroll 1
    for (int k = 0; k < 64; k += 4) {
        float4 a0 = *(const float4*)&sX[r0 + 0][k];
        float4 a1 = *(const float4*)&sX[r0 + 1][k];
        float4 a2 = *(const float4*)&sX[r0 + 2][k];
        float4 a3 = *(const float4*)&sX[r0 + 3][k];
        float2 b0 = *(const float2*)&sW[(k + 0) * 32 + c0];
        float2 b1 = *(const float2*)&sW[(k + 1) * 32 + c0];
        float2 b2 = *(const float2*)&sW[(k + 2) * 32 + c0];
        float2 b3 = *(const float2*)&sW[(k + 3) * 32 + c0];
        acc0.x += a0.x*b0.x + a0.y*b1.x + a0.z*b2.x + a0.w*b3.x;
        acc0.y += a0.x*b0.y + a0.y*b1.y + a0.z*b2.y + a0.w*b3.y;
        acc1.x += a1.x*b0.x + a1.y*b1.x + a1.z*b2.x + a1.w*b3.x;
        acc1.y += a1.x*b0.y + a1.y*b1.y + a1.z*b2.y + a1.w*b3.y;
        acc2.x += a2.x*b0.x + a2.y*b1.x + a2.z*b2.x + a2.w*b3.x;
        acc2.y += a2.x*b0.y + a2.y*b1.y + a2.z*b2.y + a2.w*b3.y;
        acc3.x += a3.x*b0.x + a3.y*b1.x + a3.z*b2.x + a3.w*b3.x;
        acc3.y += a3.x*b0.y + a3.y*b1.y + a3.z*b2.y + a3.w*b3.y;
    }
    int gr = row0 + r0;
    if (gr + 0 < N) Hb2[(long)(gr + 0) * 16 + tx] = (unsigned)f2bf(acc0.x) | ((unsigned)f2bf(acc0.y) << 16);
    if (gr + 1 < N) Hb2[(long)(gr + 1) * 16 + tx] = (unsigned)f2bf(acc1.x) | ((unsigned)f2bf(acc1.y) << 16);
    if (gr + 2 < N) Hb2[(long)(gr + 2) * 16 + tx] = (unsigned)f2bf(acc2.x) | ((unsigned)f2bf(acc2.y) << 16);
    if (gr + 3 < N) Hb2[(long)(gr + 3) * 16 + tx] = (unsigned)f2bf(acc3.x) | ((unsigned)f2bf(acc3.y) << 16);
}

// ------- gather layer 1 (C=64, bf16 h1 in, bf16 agg1 out): one wave/node -------
__global__ void k_gather1(const unsigned short* __restrict__ h1b,
                          const float* __restrict__ dis,
                          const int* __restrict__ rowptr, const int* __restrict__ deg,
                          const int* __restrict__ ecol,
                          const float* __restrict__ b1,
                          unsigned short* __restrict__ agg1b) {
    int node = (blockIdx.x << 2) + (threadIdx.x >> 6);
    int lane = threadIdx.x & 63;
    if (node >= N) return;                 // wave-uniform (N % 4 == 0)
    int q = lane & 15;
    int g = lane >> 4;
    int start = rowptr[node];
    int dgr = deg[node];
    float di = dis[node];
    float4 acc = make_float4(0.f, 0.f, 0.f, 0.f);

    for (int base = 0; base < dgr; base += 64) {
        int cnt = min(dgr - base, 64);
        int se = 0; float we = 0.f;
        if (lane < cnt) { se = ecol[start + base + lane]; we = dis[se]; }
        for (int j = 0; j < cnt; j += 8) {
            int s0 = __shfl(se, j + g);       float w0 = __shfl(we, j + g);
            int s1 = __shfl(se, j + 4 + g);   float w1 = __shfl(we, j + 4 + g);
            uint2 u0 = *(const uint2*)(h1b + ((long)s0 << 6) + (q << 2));
            uint2 u1 = *(const uint2*)(h1b + ((long)s1 << 6) + (q << 2));
            acc.x += w0 * bf_lo(u0.x) + w1 * bf_lo(u1.x);
            acc.y += w0 * bf_hi(u0.x) + w1 * bf_hi(u1.x);
            acc.z += w0 * bf_lo(u0.y) + w1 * bf_lo(u1.y);
            acc.w += w0 * bf_hi(u0.y) + w1 * bf_hi(u1.y);
        }
    }
#pragma unroll
    for (int off = 16; off <= 32; off <<= 1) {
        acc.x += __shfl_xor(acc.x, off);
        acc.y += __shfl_xor(acc.y, off);
        acc.z += __shfl_xor(acc.z, off);
        acc.w += __shfl_xor(acc.w, off);
    }
    if (g == 0) {
        uint2 uh = *(const uint2*)(h1b + ((long)node << 6) + (q << 2));
        float4 bb = *(const float4*)(b1 + q * 4);
        float rx = fmaxf(di * (acc.x + di * bf_lo(uh.x)) + bb.x, 0.f);
        float ry = fmaxf(di * (acc.y + di * bf_hi(uh.x)) + bb.y, 0.f);
        float rz = fmaxf(di * (acc.z + di * bf_lo(uh.y)) + bb.z, 0.f);
        float rw = fmaxf(di * (acc.w + di * bf_hi(uh.y)) + bb.w, 0.f);
        uint2 o;
        o.x = (unsigned)f2bf(rx) | ((unsigned)f2bf(ry) << 16);
        o.y = (unsigned)f2bf(rz) | ((unsigned)f2bf(rw) << 16);
        *(uint2*)(agg1b + ((long)node << 6) + (q << 2)) = o;
    }
}

// ------- gather layer 2 (C=32, bf16 h2) + log_softmax: one wave per node -------
__global__ void k_gather2(const unsigned short* __restrict__ h2b,
                          const float* __restrict__ dis,
                          const int* __restrict__ rowptr, const int* __restrict__ deg,
                          const int* __restrict__ ecol,
                          const float* __restrict__ b2, float* __restrict__ out) {
    int node = (blockIdx.x << 2) + (threadIdx.x >> 6);
    int lane = threadIdx.x & 63;
    if (node >= N) return;
    int q = lane & 7;
    int g = lane >> 3;
    int start = rowptr[node];
    int dgr = deg[node];
    float di = dis[node];
    float4 acc = make_float4(0.f, 0.f, 0.f, 0.f);

    for (int base = 0; base < dgr; base += 64) {
        int cnt = min(dgr - base, 64);
        int se = 0; float we = 0.f;
        if (lane < cnt) { se = ecol[start + base + lane]; we = dis[se]; }
        for (int j = 0; j < cnt; j += 16) {
            int s0 = __shfl(se, j + g);       float w0 = __shfl(we, j + g);
            int s1 = __shfl(se, j + 8 + g);   float w1 = __shfl(we, j + 8 + g);
            uint2 u0 = *(const uint2*)(h2b + ((long)s0 << 5) + (q << 2));
            uint2 u1 = *(const uint2*)(h2b + ((long)s1 << 5) + (q << 2));
            acc.x += w0 * bf_lo(u0.x) + w1 * bf_lo(u1.x);
            acc.y += w0 * bf_hi(u0.x) + w1 * bf_hi(u1.x);
            acc.z += w0 * bf_lo(u0.y) + w1 * bf_lo(u1.y);
            acc.w += w0 * bf_hi(u0.y) + w1 * bf_hi(u1.y);
        }
    }
#pragma unroll
    for (int off = 8; off <= 32; off <<= 1) {
        acc.x += __shfl_xor(acc.x, off);
        acc.y += __shfl_xor(acc.y, off);
        acc.z += __shfl_xor(acc.z, off);
        acc.w += __shfl_xor(acc.w, off);
    }
    uint2 uh = *(const uint2*)(h2b + ((long)node << 5) + (q << 2));
    float4 bb = *(const float4*)(b2 + q * 4);
    float4 v;
    v.x = di * (acc.x + di * bf_lo(uh.x)) + bb.x;
    v.y = di * (acc.y + di * bf_hi(uh.x)) + bb.y;
    v.z = di * (acc.z + di * bf_lo(uh.y)) + bb.z;
    v.w = di * (acc.w + di * bf_hi(uh.y)) + bb.w;
    float m = fmaxf(fmaxf(v.x, v.y), fmaxf(v.z, v.w));
#pragma unroll
    for (int off = 1; off <= 4; off <<= 1) m = fmaxf(m, __shfl_xor(m, off));
    float s = expf(v.x - m) + expf(v.y - m) + expf(v.z - m) + expf(v.w - m);
#pragma unroll
    for (int off = 1; off <= 4; off <<= 1) s += __shfl_xor(s, off);
    float lg = m + logf(s);
    if (g == 0) {
        float4 r;
        r.x = v.x - lg; r.y = v.y - lg; r.z = v.z - lg; r.w = v.w - lg;
        *(float4*)(out + ((long)node << 5) + q * 4) = r;
    }
}

extern "C" void kernel_launch(void* const* d_in, const int* in_sizes, int n_in,
                              void* d_out, int out_size, void* d_ws, size_t ws_size,
                              hipStream_t stream) {
    const float* x  = (const float*)d_in[0];
    const int*   ei = (const int*)d_in[1];
    const float* W1 = (const float*)d_in[2];
    const float* b1 = (const float*)d_in[3];
    const float* W2 = (const float*)d_in[4];
    const float* b2 = (const float*)d_in[5];
    float* out = (float*)d_out;

    const int* src = ei;
    const int* dst = ei + E;

    char* w = (char*)d_ws;
    int*   deg    = (int*)(w + 0);
    float* dis    = (float*)(w + (512u << 10));
    int*   rowptr = (int*)(w + (1024u << 10));
    int*   cursor = (int*)(w + (1536u << 10));
    int*   bsum   = (int*)(w + (2048u << 10));
    int*   ecol   = (int*)(w + (2560u << 10));                      // 3.2 MB
    unsigned short* h1b   = (unsigned short*)(w + (10240u << 10));  // 12.8 MB bf16
    unsigned short* agg1b = (unsigned short*)(w + (24576u << 10));  // 12.8 MB bf16
    unsigned short* h2b   = (unsigned short*)(w + (38912u << 10));  //  6.4 MB bf16

    hipMemsetAsync(deg, 0, (size_t)N * 4, stream);
    k_degree<<<GRPS * 8, 256, 0, stream>>>(dst, deg);

    k_scanA<<<NB, 256, 0, stream>>>(deg, rowptr, bsum);
    k_scanC<<<(N + 255) / 256, 256, 0, stream>>>(rowptr, bsum, cursor, deg, dis);

    // fused: partitioned place (768 blocks) overlapped with gemm64 (1563 blocks)
    k_place_gemm64<<<PLACE_BLOCKS + GEMM_BLOCKS, 256, 0, stream>>>(
        src, dst, cursor, ecol, x, W1, h1b);

    k_gather1<<<(N + 3) / 4, 256, 0, stream>>>(h1b, dis, rowptr, deg, ecol, b1, agg1b);

    k_gemm32<<<(N + 63) / 64, 256, 0, stream>>>(agg1b, W2, (unsigned*)h2b);
    k_gather2<<<(N + 3) / 4, 256, 0, stream>>>(h2b, dis, rowptr, deg, ecol, b2, out);
}